// Round 1
// baseline (2335.940 us; speedup 1.0000x reference)
//
#include <hip/hip_runtime.h>
#include <hip/hip_bf16.h>
#include <cstdint>

// ---------------------------------------------------------------------------
// SsLayer: outputs[2,B,T,OUT] (loc, softplus-scale) + state_out[B,NS]
// Plan:
//   ck_* : fp32 -> f16 conversions / layout prep (x, Bm^T, [C|D]^T, A scan layout)
//   gemm<256,0>: U = x @ Bm + b            (f16 MFMA, out f16 in ws)
//   scan       : s_{t+1} = tanh(u_t + s_t A)  64 WGs (1/batch row), A 75% in
//                VGPRs + 25% streamed from L2 each step, v_dot2_f32_f16
//   gemm<512,1>: loc = S@C + c ; scale = softplus(S@D + d)  (fp32 out)
// ---------------------------------------------------------------------------

typedef _Float16 f16;
typedef _Float16 f16x2 __attribute__((ext_vector_type(2)));
typedef _Float16 f16x4 __attribute__((ext_vector_type(4)));
typedef _Float16 f16x8 __attribute__((ext_vector_type(8)));
typedef float    f32x4 __attribute__((ext_vector_type(4)));

#define NS 512

// ws byte offsets (total ~129.3 MB). x16 shares the S16 region: x16 is dead
// after gemm1; scan then overwrites the region with S16.
#define OFF_S16   (0ull)            // 67,108,864   (S: [B*T, 512] f16)
#define OFF_X16   (0ull)            // 33,554,432   (x16 lives here during phase 1)
#define OFF_U16   (67108864ull)     // 67,108,864   (U: [B*T, 512] f16, bias added)
#define OFF_BMT   (134217728ull)    //    262,144   (Bm^T: [512][256] f16)
#define OFF_CDT   (134479872ull)    //    524,288   ([C|D]^T: [512][512] f16)
#define OFF_APREP (135004160ull)    //    393,216   (A reg-part, per-thread packed)
#define OFF_ASTR  (135397376ull)    //    131,072   (A streamed-part)

#if defined(__has_builtin)
#  if __has_builtin(__builtin_amdgcn_fdot2)
#    define HAS_FDOT2 1
#  endif
#endif

__device__ __forceinline__ float fdot2f(unsigned a, unsigned s, float c) {
#ifdef HAS_FDOT2
  return __builtin_amdgcn_fdot2(__builtin_bit_cast(f16x2, a),
                                __builtin_bit_cast(f16x2, s), c, false);
#else
  f16x2 av = __builtin_bit_cast(f16x2, a);
  f16x2 sv = __builtin_bit_cast(f16x2, s);
  return c + (float)av[0] * (float)sv[0] + (float)av[1] * (float)sv[1];
#endif
}

__device__ __forceinline__ unsigned packh2(float a, float b) {
  f16x2 h; h[0] = (f16)a; h[1] = (f16)b;
  return __builtin_bit_cast(unsigned, h);
}

// ------------------------------ prep kernels -------------------------------

__global__ void ck_x(const float* __restrict__ xg, f16* __restrict__ x16) {
  int i = (blockIdx.x * 256 + threadIdx.x) * 4;
  float4 v = *(const float4*)(xg + i);
  f16x4 h; h[0] = (f16)v.x; h[1] = (f16)v.y; h[2] = (f16)v.z; h[3] = (f16)v.w;
  *(f16x4*)(x16 + i) = h;
}

__global__ void ck_bmt(const float* __restrict__ Bm, f16* __restrict__ BmT) {
  int g = blockIdx.x * 256 + threadIdx.x;   // 131072 = 512*256
  int n = g >> 8, k = g & 255;
  BmT[g] = (f16)Bm[k * 512 + n];            // BmT[n][k]
}

__global__ void ck_cdt(const float* __restrict__ C, const float* __restrict__ D,
                       f16* __restrict__ CDT) {
  int g = blockIdx.x * 256 + threadIdx.x;   // 262144 = 512*512
  int n = g >> 9, k = g & 511;
  float v = (n < 256) ? C[k * 256 + n] : D[k * 256 + (n - 256)];
  CDT[g] = (f16)v;                          // CDT[n][k], n<256 -> C, else D
}

// A scan layout. Thread t of the scan kernel: kb=t>>6 (k-block of 64 rows),
// l=t&63; its 8 output columns are j = jj*64 + l (jj=0..7).
//  Reg part  (rows kb*64 + [0,48)): dword t*192 + p*8 + jj = pack(A[k0][j], A[k0+1][j]),
//            p=0..23, k0 = kb*64 + 2p.
//  Stream part (rows kb*64 + [48,64)): float4 idx f*512 + t (f=0..15),
//            f = pp*2 + jj2, component d: jj = jj2*4+d, k0 = kb*64+48+2*pp.
__global__ void ck_a(const float* __restrict__ Ag, unsigned* __restrict__ Aprep,
                     unsigned* __restrict__ Astr) {
  int g = blockIdx.x * 256 + threadIdx.x;   // 131072 packed dwords total
  if (g < 98304) {
    int t = g / 192, rr = g % 192;
    int p = rr >> 3, jj = rr & 7;
    int kb = t >> 6, l = t & 63;
    int r0 = kb * 64 + 2 * p;
    int j = jj * 64 + l;
    Aprep[g] = packh2(Ag[r0 * 512 + j], Ag[(r0 + 1) * 512 + j]);
  } else {
    int q = g - 98304;                      // 32768 dwords
    int F = q >> 2, d = q & 3;
    int t = F & 511, f = F >> 9;
    int pp = f >> 1, jj2 = f & 1;
    int jj = jj2 * 4 + d;
    int kb = t >> 6, l = t & 63;
    int r0 = kb * 64 + 48 + 2 * pp;
    int j = jj * 64 + l;
    Astr[q] = packh2(Ag[r0 * 512 + j], Ag[(r0 + 1) * 512 + j]);
  }
}

// ------------------------------- GEMM --------------------------------------
// C[M,128-tile] = A[M,K] @ B  with B given transposed: Bt[n][k].
// Block 256 thr = 4 waves, each wave a 64x64 quadrant, 16x16x32 f16 MFMA.
// MODE 0: out f16 = val + bias0[n]   (U)
// MODE 1: n<256 -> loc = val + bias0[n] ; else scale = softplus(val + bias1[n-256])
template <int KDIM, int MODE>
__global__ __launch_bounds__(256, 2) void gemm_kernel(
    const f16* __restrict__ Ag, const f16* __restrict__ Bt,
    const float* __restrict__ bias0, const float* __restrict__ bias1,
    void* __restrict__ outp) {
  __shared__ f16 At[128 * 40];   // 32 k + 8 pad per row (bank-conflict-free b128)
  __shared__ f16 Bs[128 * 40];
  const int tid = threadIdx.x;
  const int m0 = blockIdx.y * 128;
  const int n0 = blockIdx.x * 128;
  const int w = tid >> 6, lane = tid & 63;
  const int wm = w & 1, wn = w >> 1;
  const int r = lane & 15, qd = lane >> 4;

  f32x4 zero4 = {0.f, 0.f, 0.f, 0.f};
  f32x4 acc[4][4];
#pragma unroll
  for (int mt = 0; mt < 4; ++mt)
#pragma unroll
    for (int nt = 0; nt < 4; ++nt) acc[mt][nt] = zero4;

  for (int kk = 0; kk < KDIM; kk += 32) {
#pragma unroll
    for (int s = 0; s < 2; ++s) {
      int fi = tid * 2 + s;
      int row = fi >> 2, q = fi & 3;
      float4 av = *(const float4*)(Ag + (size_t)(m0 + row) * KDIM + kk + q * 8);
      *(float4*)(At + row * 40 + q * 8) = av;
      float4 bv = *(const float4*)(Bt + (size_t)(n0 + row) * KDIM + kk + q * 8);
      *(float4*)(Bs + row * 40 + q * 8) = bv;
    }
    __syncthreads();
    f16x8 af[4], bf[4];
#pragma unroll
    for (int mt = 0; mt < 4; ++mt)
      af[mt] = *(const f16x8*)(At + (wm * 64 + mt * 16 + r) * 40 + qd * 8);
#pragma unroll
    for (int nt = 0; nt < 4; ++nt)
      bf[nt] = *(const f16x8*)(Bs + (wn * 64 + nt * 16 + r) * 40 + qd * 8);
#pragma unroll
    for (int mt = 0; mt < 4; ++mt)
#pragma unroll
      for (int nt = 0; nt < 4; ++nt)
        acc[mt][nt] = __builtin_amdgcn_mfma_f32_16x16x32_f16(af[mt], bf[nt],
                                                             acc[mt][nt], 0, 0, 0);
    __syncthreads();
  }

#pragma unroll
  for (int mt = 0; mt < 4; ++mt) {
#pragma unroll
    for (int nt = 0; nt < 4; ++nt) {
      int n = n0 + wn * 64 + nt * 16 + r;
#pragma unroll
      for (int i = 0; i < 4; ++i) {
        int m = m0 + wm * 64 + mt * 16 + qd * 4 + i;
        float v = acc[mt][nt][i];
        if (MODE == 0) {
          ((f16*)outp)[(size_t)m * NS + n] = (f16)(v + bias0[n]);
        } else {
          if (n < 256) {
            ((float*)outp)[(size_t)m * 256 + n] = v + bias0[n];
          } else {
            float z = v + bias1[n - 256];
            float sp = (z > 20.f) ? z : log1pf(__expf(z));
            ((float*)outp)[16777216ull + (size_t)m * 256 + (n - 256)] = sp;
          }
        }
      }
    }
  }
}

// ------------------------------- scan --------------------------------------

#define BCU(x) __builtin_bit_cast(unsigned, (x))

#define REGDOT(P, SC)                                   \
  do {                                                  \
    unsigned sb_ = BCU(SC);                             \
    float4 a0_ = areg[(P) * 2], a1_ = areg[(P) * 2 + 1];\
    acc0 = fdot2f(BCU(a0_.x), sb_, acc0);               \
    acc1 = fdot2f(BCU(a0_.y), sb_, acc1);               \
    acc2 = fdot2f(BCU(a0_.z), sb_, acc2);               \
    acc3 = fdot2f(BCU(a0_.w), sb_, acc3);               \
    acc4 = fdot2f(BCU(a1_.x), sb_, acc4);               \
    acc5 = fdot2f(BCU(a1_.y), sb_, acc5);               \
    acc6 = fdot2f(BCU(a1_.z), sb_, acc6);               \
    acc7 = fdot2f(BCU(a1_.w), sb_, acc7);               \
  } while (0)

#define GAPDOT(LO, HI, SC)                              \
  do {                                                  \
    unsigned sb_ = BCU(SC);                             \
    acc0 = fdot2f(BCU((LO).x), sb_, acc0);              \
    acc1 = fdot2f(BCU((LO).y), sb_, acc1);              \
    acc2 = fdot2f(BCU((LO).z), sb_, acc2);              \
    acc3 = fdot2f(BCU((LO).w), sb_, acc3);              \
    acc4 = fdot2f(BCU((HI).x), sb_, acc4);              \
    acc5 = fdot2f(BCU((HI).y), sb_, acc5);              \
    acc6 = fdot2f(BCU((HI).z), sb_, acc6);              \
    acc7 = fdot2f(BCU((HI).w), sb_, acc7);              \
  } while (0)

__global__ __launch_bounds__(512, 2) void scan_kernel(
    const float4* __restrict__ Aprep4, const float4* __restrict__ Astr4,
    const f16* __restrict__ U16, f16* __restrict__ S16,
    float* __restrict__ stout) {
  __shared__ float part[4096];                       // [kb][j] partials, 16 KB
  __shared__ __align__(16) unsigned sf16[256];       // s packed f16x2
  const int t = threadIdx.x;
  const int b = blockIdx.x;
  const int kb = t >> 6;

  // A register part: 192 packed dwords (48 float4) per thread, live whole kernel
  float4 areg[48];
#pragma unroll
  for (int i = 0; i < 48; ++i) areg[i] = Aprep4[t * 48 + i];

  if (t < 256) sf16[t] = 0u;                         // s_0 = 0
  __syncthreads();

  const float4* sp4 = (const float4*)sf16;

#pragma unroll 1
  for (int ts = 0; ts < 1024; ++ts) {
    // opaque zero: prevents LICM from hoisting the (loop-invariant) A-stream
    // loads out of the loop, which would blow the register budget
    int zoff;
    asm volatile("s_mov_b32 %0, 0" : "=s"(zoff));
    const float4* astr = Astr4 + zoff;

    const int row = b * 1024 + ts;
    f16 uh = U16[(size_t)row * 512 + t];             // u_t[j=t], issued early

    // stream first half of the A gap (rows 48..55 of this k-block)
    float4 gA0 = astr[0 * 512 + t], gA1 = astr[1 * 512 + t];
    float4 gA2 = astr[2 * 512 + t], gA3 = astr[3 * 512 + t];
    float4 gA4 = astr[4 * 512 + t], gA5 = astr[5 * 512 + t];
    float4 gA6 = astr[6 * 512 + t], gA7 = astr[7 * 512 + t];

    float acc0 = 0.f, acc1 = 0.f, acc2 = 0.f, acc3 = 0.f;
    float acc4 = 0.f, acc5 = 0.f, acc6 = 0.f, acc7 = 0.f;

    // register part: k rows kb*64 + [0,48)
#pragma unroll
    for (int c = 0; c < 6; ++c) {
      float4 s4 = sp4[kb * 8 + c];                   // wave-uniform broadcast
      REGDOT(c * 4 + 0, s4.x);
      REGDOT(c * 4 + 1, s4.y);
      REGDOT(c * 4 + 2, s4.z);
      REGDOT(c * 4 + 3, s4.w);
    }

    // streamed part: k rows kb*64 + [48,64)
    float4 s4a = sp4[kb * 8 + 6], s4b = sp4[kb * 8 + 7];
    GAPDOT(gA0, gA1, s4a.x);
    GAPDOT(gA2, gA3, s4a.y);
    GAPDOT(gA4, gA5, s4a.z);
    GAPDOT(gA6, gA7, s4a.w);
    gA0 = astr[8 * 512 + t];  gA1 = astr[9 * 512 + t];
    gA2 = astr[10 * 512 + t]; gA3 = astr[11 * 512 + t];
    gA4 = astr[12 * 512 + t]; gA5 = astr[13 * 512 + t];
    gA6 = astr[14 * 512 + t]; gA7 = astr[15 * 512 + t];
    GAPDOT(gA0, gA1, s4b.x);
    GAPDOT(gA2, gA3, s4b.y);
    GAPDOT(gA4, gA5, s4b.z);
    GAPDOT(gA6, gA7, s4b.w);

    // partials: [kb][j], j = jj*64 + l -> lanes write consecutive dwords (no conflict)
    {
      const int l = t & 63;
      part[kb * 512 + 0 * 64 + l] = acc0;
      part[kb * 512 + 1 * 64 + l] = acc1;
      part[kb * 512 + 2 * 64 + l] = acc2;
      part[kb * 512 + 3 * 64 + l] = acc3;
      part[kb * 512 + 4 * 64 + l] = acc4;
      part[kb * 512 + 5 * 64 + l] = acc5;
      part[kb * 512 + 6 * 64 + l] = acc6;
      part[kb * 512 + 7 * 64 + l] = acc7;
    }
    __syncthreads();

    // reduce over k-blocks for column j = t, add u, tanh
    float sum = (float)uh;
#pragma unroll
    for (int k2 = 0; k2 < 8; ++k2) sum += part[k2 * 512 + t];
    float e = __expf(2.f * sum);
    float ns = 1.f - 2.f / (e + 1.f);                // tanh(sum)

    S16[(size_t)row * 512 + t] = (f16)ns;            // new_state (for loc/scale GEMM)
    if (ts == 1022) stout[b * 512 + t] = ns;         // prev_states[-1] = s_{1023}

    // repack s as f16x2 pairs without an extra barrier
    float pn = __shfl_xor(ns, 1, 64);
    if (!(t & 1)) sf16[t >> 1] = packh2(ns, pn);
    __syncthreads();
  }
}

// ------------------------------ launcher -----------------------------------

extern "C" void kernel_launch(void* const* d_in, const int* in_sizes, int n_in,
                              void* d_out, int out_size, void* d_ws, size_t ws_size,
                              hipStream_t stream) {
  (void)in_sizes; (void)n_in; (void)out_size; (void)ws_size;
  const float* xg  = (const float*)d_in[0];
  const float* Ag  = (const float*)d_in[1];
  const float* Bmg = (const float*)d_in[2];
  const float* bg  = (const float*)d_in[3];
  const float* Cg  = (const float*)d_in[4];
  const float* cg  = (const float*)d_in[5];
  const float* Dg  = (const float*)d_in[6];
  const float* dg  = (const float*)d_in[7];

  char* w = (char*)d_ws;
  f16* x16 = (f16*)(w + OFF_X16);
  f16* U16 = (f16*)(w + OFF_U16);
  f16* S16 = (f16*)(w + OFF_S16);
  f16* BmT = (f16*)(w + OFF_BMT);
  f16* CDT = (f16*)(w + OFF_CDT);
  unsigned* Aprep = (unsigned*)(w + OFF_APREP);
  unsigned* Astr  = (unsigned*)(w + OFF_ASTR);
  float* out = (float*)d_out;

  ck_x  <<<16384, 256, 0, stream>>>(xg, x16);
  ck_bmt<<<  512, 256, 0, stream>>>(Bmg, BmT);
  ck_cdt<<< 1024, 256, 0, stream>>>(Cg, Dg, CDT);
  ck_a  <<<  512, 256, 0, stream>>>(Ag, Aprep, Astr);

  // U = x @ Bm + b
  gemm_kernel<256, 0><<<dim3(4, 512), 256, 0, stream>>>(x16, BmT, bg, nullptr,
                                                        (void*)U16);
  // sequential scan (overwrites x16 region with S16)
  scan_kernel<<<64, 512, 0, stream>>>((const float4*)Aprep, (const float4*)Astr,
                                      U16, S16, out + 33554432);
  // loc / softplus(scale) from S
  gemm_kernel<512, 1><<<dim3(4, 512), 256, 0, stream>>>(S16, CDT, cg, dg,
                                                        (void*)out);
}